// Round 3
// baseline (244.706 us; speedup 1.0000x reference)
//
#include <hip/hip_runtime.h>

// EMA chunked scan + inverse-gather broadcast for DeChunkLayer (R12).
// R12 = R11 (best, 198.6 us) restructured: single fused kernel with
// flag-gated decoupled lookback, x-chunk held in registers.
//
// Why: R11 proved block c needs only ~1 predecessor chunk (weight < 2^-40
// beyond that). The 2-kernel split existed to materialize ALL chunk states
// before consumers; that's now obsolete. Fusing removes (a) the 2nd x read
// (64 MiB L3, on the scan critical path), (b) one kernel launch + full
// K1-tail->K2-head serialization, (c) Bbuf round-trip latency.
// Safety: 512 blocks = exact 2/CU capacity (all co-resident); ticket-based
// virtual block IDs make wait targets always-already-running (rocPRIM
// lookback pattern); agent-scope release/acquire atomics handle cross-XCD
// L2 non-coherence; flags+ticket reset via capture-safe hipMemsetAsync.
// Numerics: identical scan op order to R11 -> absmax should stay 0.015625.
// Predict: kernel ~70 -> ~40-45 us => dur 198.6 -> ~168-178. Regression =>
// VGPR spill (fallback: re-read x from L3). Fail => race (revert to R11).
//
// x: (1, 16384, 1024) f32, p_selected: (16384,) f32, b: (1, 32768) i32
// out: (1, 32768, 1024) f32
// z_t = (1-p_t) z_{t-1} + p_t x_t  (p clipped to [1e-4, 1-1e-4])
// out[f] = z[t] for f in [pos[t], pos[t+1])

#define DCH 1024
#define L_COMP 16384
#define L_FULL 32768
#define CHUNK 32
#define NCHUNK (L_COMP / CHUNK)   // 512
#define SEG (L_FULL / NCHUNK)     // 64 b-elements per segment
#define EPSV 1e-4f
#define WMIN 1e-12f               // ~2^-40 lookback window (matches R11)

typedef float v4f __attribute__((ext_vector_type(4)));

__device__ __forceinline__ float clipp(float p) {
    p = fmaxf(p, EPSV);
    return fminf(p, 1.0f - EPSV);
}

__global__ __launch_bounds__(256, 2) void fused_kernel(
    const float* __restrict__ x, const float* __restrict__ p,
    const int* __restrict__ b, float* __restrict__ out,
    float* __restrict__ Bbuf, float* __restrict__ Apub,
    int* __restrict__ flag, int* __restrict__ ticket) {
    const int tid = threadIdx.x;
    const int lane = tid & 63;
    const int wave = tid >> 6;

    __shared__ int bpref[NCHUNK + 1];
    __shared__ int spos[CHUNK + 1];
    __shared__ int wtot[4];
    __shared__ int vcs;

    // Virtual block id = arrival order: wait targets are always running.
    if (tid == 0) vcs = atomicAdd(ticket, 1);
    __syncthreads();
    const int c = vcs;
    const int base = c * CHUNK;

    // (1) x chunk -> registers; local scan (zero init); publish B_c, A_c.
    v4f xv[CHUNK];           // 128 VGPRs, static indexing only (rule #20)
    v4f h = (v4f)0.f;
    float aprod = 1.0f;
    {
        const v4f* x4 = reinterpret_cast<const v4f*>(x) + (size_t)base * (DCH / 4) + tid;
#pragma unroll
        for (int ib = 0; ib < CHUNK; ib += 8) {
            float pvv[8];
#pragma unroll
            for (int j = 0; j < 8; ++j) {
                xv[ib + j] = x4[(ib + j) * (DCH / 4)];
                pvv[j] = clipp(p[base + ib + j]);   // uniform -> scalar load
            }
#pragma unroll
            for (int j = 0; j < 8; ++j) {
                float a = 1.0f - pvv[j];
                h = a * h + pvv[j] * xv[ib + j];
                aprod *= a;
            }
        }
    }
    reinterpret_cast<v4f*>(Bbuf)[c * (DCH / 4) + tid] = h;
    if (tid == 0) Apub[c] = aprod;
    __syncthreads();   // compiler drains vmcnt before s_barrier: stores done
    if (tid == 0) {
        __threadfence();  // agent-scope release: L2 writeback for cross-XCD
        __hip_atomic_store(&flag[c], 1, __ATOMIC_RELEASE, __HIP_MEMORY_SCOPE_AGENT);
    }

    // (2) redundant b popcount (replaces K1's bsum) + exclusive prefix.
    //     Each thread owns segments 2*tid, 2*tid+1: 32 int4 loads from L2.
    {
        const int4* b4 = reinterpret_cast<const int4*>(b);
        int v0 = 0, v1 = 0;
#pragma unroll 4
        for (int q = 0; q < SEG / 4; ++q) {
            int4 w0 = b4[(2 * tid) * (SEG / 4) + q];
            int4 w1 = b4[(2 * tid + 1) * (SEG / 4) + q];
            v0 += w0.x + w0.y + w0.z + w0.w;
            v1 += w1.x + w1.y + w1.z + w1.w;
        }
        int s = v0 + v1;
        int incl = s;
#pragma unroll
        for (int off = 1; off < 64; off <<= 1) {
            int n = __shfl_up(incl, off, 64);
            if (lane >= off) incl += n;
        }
        if (lane == 63) wtot[wave] = incl;
        __syncthreads();
        int woff = 0;
        for (int w = 0; w < wave; ++w) woff += wtot[w];
        int ex = woff + incl - s;   // exclusive prefix of this thread's pair
        bpref[2 * tid] = ex;
        bpref[2 * tid + 1] = ex + v0;
        if (tid == 0) bpref[NCHUNK] = L_COMP;
        __syncthreads();
    }

    // (3) rank-select this chunk's 33 pos values (threads 0..32)
    if (tid <= CHUNK) {
        int t = base + tid; // global one-rank (0-indexed)
        int posv = L_FULL;
        if (t < L_COMP) {
            int lo = 0, hi = NCHUNK;
            while (hi - lo > 1) {
                int mid = (lo + hi) >> 1;
                if (bpref[mid] <= t) lo = mid; else hi = mid;
            }
            int lr = t - bpref[lo]; // local rank within segment lo
            const int4* bseg = reinterpret_cast<const int4*>(b) + lo * (SEG / 4);
            int cnt = 0;
#pragma unroll 4
            for (int q = 0; q < SEG / 4; ++q) {
                int4 w = bseg[q];
                if (w.x) { if (cnt == lr) posv = lo * SEG + 4 * q + 0; ++cnt; }
                if (w.y) { if (cnt == lr) posv = lo * SEG + 4 * q + 1; ++cnt; }
                if (w.z) { if (cnt == lr) posv = lo * SEG + 4 * q + 2; ++cnt; }
                if (w.w) { if (cnt == lr) posv = lo * SEG + 4 * q + 3; ++cnt; }
            }
        }
        spos[tid] = posv;
    }
    __syncthreads();

    // (4) windowed flag-gated lookback: h_pre = sum_k w_k B_k, w_k < 2^-40
    //     dropped. Typically 1 iteration on this data; degrades gracefully.
    v4f hpre = (v4f)0.f;
    {
        float w = 1.0f;
        const v4f* B4 = reinterpret_cast<const v4f*>(Bbuf) + tid;
        for (int k = c - 1; k >= 0; --k) {
            if (w < WMIN) break;    // uniform branch (w identical all lanes)
            while (__hip_atomic_load(&flag[k], __ATOMIC_ACQUIRE,
                                     __HIP_MEMORY_SCOPE_AGENT) == 0)
                __builtin_amdgcn_s_sleep(1);
            v4f bk = B4[k * (DCH / 4)];   // ordered after acquire
            float ak = Apub[k];
            hpre += w * bk;
            w *= ak;
        }
    }

    // (5) final scan from registers (no x re-read); ranged NT broadcast.
    {
        v4f hh = hpre;
        v4f* out4 = reinterpret_cast<v4f*>(out) + tid;
        int f0 = spos[0];
#pragma unroll
        for (int t = 0; t < CHUNK; ++t) {
            float pt = clipp(p[base + t]);   // L1-warm scalar
            float a = 1.0f - pt;
            hh = a * hh + pt * xv[t];
            int fe = spos[t + 1];
            for (int f = f0; f < fe; ++f)
                __builtin_nontemporal_store(hh, &out4[(size_t)f * (DCH / 4)]);
            f0 = fe;
        }
    }
}

extern "C" void kernel_launch(void* const* d_in, const int* in_sizes, int n_in,
                              void* d_out, int out_size, void* d_ws, size_t ws_size,
                              hipStream_t stream) {
    const float* x = (const float*)d_in[0];
    const float* p = (const float*)d_in[1];
    const int* b = (const int*)d_in[2];
    float* out = (float*)d_out;

    char* ws = (char*)d_ws;
    float* Apub = (float*)ws;                  // NCHUNK floats (2 KiB)
    int* flag = (int*)(ws + 4096);             // NCHUNK ints (2 KiB)
    int* ticket = (int*)(ws + 6144);           // 1 int
    float* Bbuf = (float*)(ws + 8192);         // NCHUNK*DCH floats (2 MiB)

    // Reset flags + ticket every launch (ws may be poisoned between iters).
    // hipMemsetAsync on the capture stream is graph-capture-safe.
    hipMemsetAsync(ws + 4096, 0, 4096, stream);
    fused_kernel<<<NCHUNK, 256, 0, stream>>>(x, p, b, out, Bbuf, Apub, flag, ticket);
}

// Round 4
// 204.187 us; speedup vs baseline: 1.1984x; 1.1984x over previous
//
#include <hip/hip_runtime.h>

// EMA chunked scan + inverse-gather broadcast for DeChunkLayer (R13).
// R13 = single fused kernel, STATELESS windowed replay. No Bbuf, no flags,
// no ticket, no fences, no spin, no memset — zero inter-block communication.
//
// Why: R11 proved the lookback window is ~1 chunk (terms < 2^-40 dropped;
// tol absmax 2^-6). R12 fused with flag-gated lookback but spilled xv[32]
// to scratch (VGPR=104 < 128) -> 83 us of stall, 244.7 us total. Fix: the
// predecessor state is recomputable from x,p directly — block c walks chunk
// decay products back through p (uniform scalar) to find kstart, scans x
// forward from kstart*32 with h=0 (warmup, no stores; L3 hits — neighbor
// block fetches same chunk from HBM), then scans its own chunk with NT
// broadcast stores. Same inclusion rule as R11/R12; forward zero-init scan
// == weighted sum. Worst-case data degrades to O(c) x replay (same gamble
// as R11; bench W~1). No xv array -> ~70 VGPR, no spill.
// Predict: kernel 110 -> 40-55 us (HBM floor ~31), FETCH ~35-65 MiB,
// WRITE ~130 MiB, VGPR 64-80 => dur 244.7 -> ~170-185 (beats R11 198.6).
// If >= R11: stall wasn't spill/sync -> revert to R11, attack store path.
//
// x: (1, 16384, 1024) f32, p_selected: (16384,) f32, b: (1, 32768) i32
// out: (1, 32768, 1024) f32
// z_t = (1-p_t) z_{t-1} + p_t x_t  (p clipped to [1e-4, 1-1e-4])
// out[f] = z[t] for f in [pos[t], pos[t+1])

#define DCH 1024
#define L_COMP 16384
#define L_FULL 32768
#define CHUNK 32
#define NCHUNK (L_COMP / CHUNK)   // 512
#define SEG (L_FULL / NCHUNK)     // 64 b-elements per segment
#define EPSV 1e-4f
#define WMIN 1e-12f               // ~2^-40 lookback window (matches R11/R12)

typedef float v4f __attribute__((ext_vector_type(4)));

__device__ __forceinline__ float clipp(float p) {
    p = fmaxf(p, EPSV);
    return fminf(p, 1.0f - EPSV);
}

__global__ __launch_bounds__(256, 2) void fused_kernel(
    const float* __restrict__ x, const float* __restrict__ p,
    const int* __restrict__ b, float* __restrict__ out) {
    const int c = blockIdx.x;
    const int tid = threadIdx.x;
    const int lane = tid & 63;
    const int wave = tid >> 6;
    const int base = c * CHUNK;

    __shared__ int bpref[NCHUNK + 1];
    __shared__ int spos[CHUNK + 1];
    __shared__ int wtot[4];

    // (a) redundant b popcount + block-local exclusive prefix over 512 segs.
    //     Each thread owns segments 2*tid, 2*tid+1: 32 int4 loads (L2-warm).
    {
        const int4* b4 = reinterpret_cast<const int4*>(b);
        int v0 = 0, v1 = 0;
#pragma unroll 4
        for (int q = 0; q < SEG / 4; ++q) {
            int4 w0 = b4[(2 * tid) * (SEG / 4) + q];
            int4 w1 = b4[(2 * tid + 1) * (SEG / 4) + q];
            v0 += w0.x + w0.y + w0.z + w0.w;
            v1 += w1.x + w1.y + w1.z + w1.w;
        }
        int s = v0 + v1;
        int incl = s;
#pragma unroll
        for (int off = 1; off < 64; off <<= 1) {
            int n = __shfl_up(incl, off, 64);
            if (lane >= off) incl += n;
        }
        if (lane == 63) wtot[wave] = incl;
        __syncthreads();
        int woff = 0;
        for (int w = 0; w < wave; ++w) woff += wtot[w];
        int ex = woff + incl - s;   // exclusive prefix of this thread's pair
        bpref[2 * tid] = ex;
        bpref[2 * tid + 1] = ex + v0;
        if (tid == 0) bpref[NCHUNK] = L_COMP;
        __syncthreads();
    }

    // (b) rank-select this chunk's 33 pos values (threads 0..32)
    if (tid <= CHUNK) {
        int t = base + tid; // global one-rank (0-indexed)
        int posv = L_FULL;
        if (t < L_COMP) {
            int lo = 0, hi = NCHUNK;
            while (hi - lo > 1) {
                int mid = (lo + hi) >> 1;
                if (bpref[mid] <= t) lo = mid; else hi = mid;
            }
            int lr = t - bpref[lo]; // local rank within segment lo
            const int4* bseg = reinterpret_cast<const int4*>(b) + lo * (SEG / 4);
            int cnt = 0;
#pragma unroll 4
            for (int q = 0; q < SEG / 4; ++q) {
                int4 w = bseg[q];
                if (w.x) { if (cnt == lr) posv = lo * SEG + 4 * q + 0; ++cnt; }
                if (w.y) { if (cnt == lr) posv = lo * SEG + 4 * q + 1; ++cnt; }
                if (w.z) { if (cnt == lr) posv = lo * SEG + 4 * q + 2; ++cnt; }
                if (w.w) { if (cnt == lr) posv = lo * SEG + 4 * q + 3; ++cnt; }
            }
        }
        spos[tid] = posv;
    }
    __syncthreads();

    // (c) window-find: walk chunk decay products backwards through p.
    //     Chunk k included iff prod_{j=k+1..c-1} A_j >= WMIN (same rule as
    //     R12's lookback). Uniform scalar work, ~32*W mults; W~1 on bench.
    int kstart = c;
    {
        float w = 1.0f;
        while (kstart > 0 && w >= WMIN) {
            --kstart;
            float ap = 1.0f;
#pragma unroll 8
            for (int t = 0; t < CHUNK; ++t)
                ap *= (1.0f - clipp(p[kstart * CHUNK + t]));
            w *= ap;
        }
    }

    // (d) forward scan from row kstart*32 with h=0: warmup rows (no stores,
    //     x mostly L3-hit), then chunk c's rows with ranged NT broadcast.
    {
        const v4f* x4 = reinterpret_cast<const v4f*>(x) + tid;
        v4f h = (v4f)0.f;
        for (int r = kstart * CHUNK; r < base; r += 8) {
            v4f xv[8];
            float pv[8];
#pragma unroll
            for (int j = 0; j < 8; ++j) {
                xv[j] = x4[(size_t)(r + j) * (DCH / 4)];
                pv[j] = clipp(p[r + j]);            // uniform -> scalar
            }
#pragma unroll
            for (int j = 0; j < 8; ++j) {
                float a = 1.0f - pv[j];
                h = a * h + pv[j] * xv[j];
            }
        }
        v4f* out4 = reinterpret_cast<v4f*>(out) + tid;
        int f0 = spos[0];
        for (int ib = 0; ib < CHUNK; ib += 8) {
            v4f xv[8];
            float pv[8];
            int fe[8];
#pragma unroll
            for (int j = 0; j < 8; ++j) {
                xv[j] = x4[(size_t)(base + ib + j) * (DCH / 4)];
                pv[j] = clipp(p[base + ib + j]);    // uniform -> scalar
                fe[j] = spos[ib + j + 1];           // LDS
            }
#pragma unroll
            for (int j = 0; j < 8; ++j) {
                float a = 1.0f - pv[j];
                h = a * h + pv[j] * xv[j];
                for (int f = f0; f < fe[j]; ++f) {
                    __builtin_nontemporal_store(h, &out4[(size_t)f * (DCH / 4)]);
                }
                f0 = fe[j];
            }
        }
    }
}

extern "C" void kernel_launch(void* const* d_in, const int* in_sizes, int n_in,
                              void* d_out, int out_size, void* d_ws, size_t ws_size,
                              hipStream_t stream) {
    const float* x = (const float*)d_in[0];
    const float* p = (const float*)d_in[1];
    const int* b = (const int*)d_in[2];
    float* out = (float*)d_out;
    (void)d_ws; (void)ws_size;

    fused_kernel<<<NCHUNK, 256, 0, stream>>>(x, p, b, out);
}